// Round 2
// baseline (2838.963 us; speedup 1.0000x reference)
//
#include <hip/hip_runtime.h>
#include <hip/hip_fp16.h>

typedef _Float16 f16;
typedef __attribute__((ext_vector_type(8))) _Float16 f16x8;
typedef __attribute__((ext_vector_type(4))) _Float16 f16x4;
typedef __attribute__((ext_vector_type(4))) float fx4;

#define DEV static __device__ __forceinline__

#define Bc   4
#define Tc   1024
#define Dc   1024
#define Hc   16
#define DHc  64
#define DFFc 4096
#define Rc   8
#define BTc  4096
#define NTOKc 4194304ull   // BTc*Dc

DEV float gelu_f(float x){ return 0.5f*x*(1.0f+erff(x*0.70710678118654752f)); }
DEV float sigmoid_f(float x){ return 1.0f/(1.0f+__expf(-x)); }

#if defined(__has_builtin)
#if __has_builtin(__builtin_amdgcn_global_load_lds)
#define HAVE_GLL 1
#endif
#endif
#ifndef HAVE_GLL
#define HAVE_GLL 0
#endif

// stage 16 bytes per lane into LDS. global_load_lds dest is wave-uniform
// base + lane*16 (m104); fallback path does reg round-trip.
DEV void stage16(const f16* g, f16* lds_base, int lane){
#if HAVE_GLL
  __builtin_amdgcn_global_load_lds((const __attribute__((address_space(1))) void*)g,
                                   (__attribute__((address_space(3))) void*)lds_base,
                                   16, 0, 0);
  (void)lane;
#else
  *(f16x8*)(lds_base + lane*8) = *(const f16x8*)g;
#endif
}

enum { KQKV=0, KWO=1, KFF1=2, KFF2=3 };

// ---------------------------------------------------------------------------
// f16 MFMA GEMM, BMT x 128 tile, BK=32, 4 waves, fp32 accum (m97 structure).
// A: MxK row-major f16.  Bt: NxK row-major f16 (B transposed).
// Epilogue per `kind`. KQKV writes fused q/k/v (N=3072) into (B,H,T,DH).
// ---------------------------------------------------------------------------
template<int BMT>
__global__ __launch_bounds__(256) void gemm_f16(
    const f16* __restrict__ A, const f16* __restrict__ Bt,
    const float* __restrict__ bias0, const float* __restrict__ bias1,
    const float* __restrict__ bias2,
    const int* __restrict__ didx, int hop,
    int M, int N, int K, int kind,
    const float* __restrict__ add0, const float* __restrict__ gmp,
    float* __restrict__ outF, f16* __restrict__ outH)
{
  __shared__ __align__(16) f16 sA[BMT*32];
  __shared__ __align__(16) f16 sB[128*32];

  constexpr int ACH = BMT/16;      // A chunks of 1KB (16 rows x 32 f16)
  constexpr int NCH = ACH + 8;     // + 8 B chunks
  constexpr int CPW = NCH/4;       // chunks per wave
  constexpr int NWM = BMT/64;      // waves along M (2 or 1)
  constexpr int NWN = 4/NWM;       // waves along N (2 or 4)
  constexpr int WCW = 128/NWN;     // per-wave col width (64 or 32)
  constexpr int NF  = WCW/16;      // n-frags per wave (4 or 2)

  int nbx = gridDim.x, nby = gridDim.y;
  int nwg = nbx*nby;                       // multiple of 8 in all our launches
  int bid = blockIdx.y*nbx + blockIdx.x;
  int cpx = nwg >> 3;
  int sid = (bid & 7)*cpx + (bid >> 3);    // bijective XCD swizzle
  int bx = sid % nbx, by = sid / nbx;
  int col0 = bx << 7, row0 = by * BMT;

  int tid = threadIdx.x;
  int w = tid >> 6, l = tid & 63;

  fx4 acc[4][NF];
  #pragma unroll
  for (int m=0;m<4;++m)
    #pragma unroll
    for (int n=0;n<NF;++n) acc[m][n] = (fx4){0.f,0.f,0.f,0.f};

  int wr = (w/NWN)*64, wc = (w%NWN)*WCW;
  int lr = l & 15, kk = (l >> 4) << 3;
  int lrow = l >> 2, kO = (l&3)*8;

  for (int k0 = 0; k0 < K; k0 += 32) {
    __syncthreads();
    #pragma unroll
    for (int cc=0; cc<CPW; ++cc) {
      int c = w*CPW + cc;
      if (c < ACH) {
        stage16(A  + (size_t)(row0 + c*16 + lrow)*K + k0 + kO, &sA[c*512], l);
      } else {
        int cb = c - ACH;
        stage16(Bt + (size_t)(col0 + cb*16 + lrow)*K + k0 + kO, &sB[cb*512], l);
      }
    }
    __syncthreads();   // compiler emits vmcnt(0) drain here

    f16x8 af[4], bf[NF];
    #pragma unroll
    for (int m=0;m<4;++m) af[m] = *(const f16x8*)&sA[(wr + m*16 + lr)*32 + kk];
    #pragma unroll
    for (int n=0;n<NF;++n) bf[n] = *(const f16x8*)&sB[(wc + n*16 + lr)*32 + kk];
    #pragma unroll
    for (int m=0;m<4;++m)
      #pragma unroll
      for (int n=0;n<NF;++n)
        acc[m][n] = __builtin_amdgcn_mfma_f32_16x16x32_f16(af[m], bf[n], acc[m][n], 0,0,0);
  }

  int room = didx[hop];
  float gmv = (kind == KFF2) ? *gmp : 0.f;

  #pragma unroll
  for (int n=0;n<NF;++n) {
    int col = col0 + wc + n*16 + lr;
    float bv;
    if (kind == KQKV) {
      int which = col >> 10, cc = col & 1023;
      const float* bb = (which==0) ? bias0 : (which==1) ? bias1 : bias2;
      bv = bb[room*1024 + cc];
    } else {
      bv = bias0[(size_t)room*N + col];
    }
    #pragma unroll
    for (int m=0;m<4;++m) {
      int rbase = row0 + wr + m*16 + ((l>>4)<<2);
      #pragma unroll
      for (int r=0;r<4;++r) {
        int row = rbase + r;                       // D: row=(lane>>4)*4+reg, col=lane&15
        float val = acc[m][n][r] + bv;
        if (kind == KQKV) {
          int which = col >> 10, cc = col & 1023;
          if (which == 0) val *= 0.125f;           // q folds 1/sqrt(DH)
          int b = row >> 10, t = row & 1023;
          int h = cc >> 6,  dh = cc & 63;
          outF[(size_t)which*NTOKc + (((size_t)((b<<4)+h) << 10) + t)*64 + dh] = val;
        } else if (kind == KWO) {
          size_t o = (size_t)row*N + col;
          outF[o] = val + add0[o];                 // xo = xg + o@wo + bo
        } else if (kind == KFF1) {
          outH[(size_t)row*N + col] = (f16)gelu_f(val);
        } else {                                   // KFF2: final room mix
          size_t o = (size_t)row*N + col;
          float v2 = add0[o] + val;                // xo + ffn
          float xold = outF[o];
          outF[o] = xold + gmv*(v2 - xold);        // x + gm*(xo2 - x)
        }
      }
    }
  }
}

// ---------------------------------------------------------------------------
// weight transpose+convert: W (room-indexed, K x N fp32) -> Wt (N x K f16)
// ---------------------------------------------------------------------------
DEV void wconv_body(const float* W, f16* Wt, int K, int N, int bx, int by, int tid)
{
  __shared__ float tile[64][65];
  int n0 = bx << 6, k0 = by << 6;
  int lrow = tid >> 4, lcol = (tid & 15) << 2;
  #pragma unroll
  for (int p=0;p<4;++p) {
    int kr = lrow + p*16;
    fx4 v = *(const fx4*)&W[(size_t)(k0+kr)*N + n0 + lcol];
    tile[kr][lcol]   = v[0]; tile[kr][lcol+1] = v[1];
    tile[kr][lcol+2] = v[2]; tile[kr][lcol+3] = v[3];
  }
  __syncthreads();
  #pragma unroll
  for (int p=0;p<4;++p) {
    int nr = lrow + p*16;
    f16x4 h;
    h[0] = (f16)tile[lcol  ][nr];
    h[1] = (f16)tile[lcol+1][nr];
    h[2] = (f16)tile[lcol+2][nr];
    h[3] = (f16)tile[lcol+3][nr];
    *(f16x4*)&Wt[(size_t)(n0+nr)*K + k0 + lcol] = h;
  }
}

__global__ __launch_bounds__(256) void wconv(
    const float* __restrict__ Wbase, f16* __restrict__ Wt,
    const int* __restrict__ didx, int hop, int K, int N)
{
  const float* W = Wbase + (size_t)didx[hop]*K*N;
  wconv_body(W, Wt, K, N, blockIdx.x, blockIdx.y, threadIdx.x);
}

// four 1024x1024 weights in one launch (z selects)
__global__ __launch_bounds__(256) void wconv4(
    const float* __restrict__ w0, const float* __restrict__ w1,
    const float* __restrict__ w2, const float* __restrict__ w3,
    f16* __restrict__ d0, f16* __restrict__ d1,
    f16* __restrict__ d2, f16* __restrict__ d3,
    const int* __restrict__ didx, int hop)
{
  int z = blockIdx.z;
  const float* W = (z==0?w0:z==1?w1:z==2?w2:w3) + (size_t)didx[hop]*1024*1024;
  f16* Wt = (z==0?d0:z==1?d1:z==2?d2:d3);
  wconv_body(W, Wt, 1024, 1024, blockIdx.x, blockIdx.y, threadIdx.x);
}

// ---------------------------------------------------------------------------
// row mean over T (two-stage)
// ---------------------------------------------------------------------------
__global__ void rowmean_s1(const float* __restrict__ x, float* __restrict__ part)
{
  int b = blockIdx.x, dc = blockIdx.y, tc = blockIdx.z;
  int d = (dc<<8) + threadIdx.x;
  const float* p = x + ((size_t)b*Tc + tc*128)*Dc + d;
  float s = 0.f;
  #pragma unroll 4
  for (int t=0;t<128;++t) s += p[(size_t)t*Dc];
  part[((b*8 + tc)<<10) + d] = s;
}

__global__ void rowmean_s2(const float* __restrict__ part, float* __restrict__ ctx,
                           float* __restrict__ gm)
{
  int b = blockIdx.x; int d = (blockIdx.y<<8) + threadIdx.x;
  float s = 0.f;
  #pragma unroll
  for (int c=0;c<8;++c) s += part[((b*8+c)<<10)+d];
  ctx[(b<<10)+d] = s * (1.0f/1024.0f);
  if (threadIdx.x==0 && b==0 && blockIdx.y==0 && gm) *gm = 0.f;
}

// ctx0 @ ctx_w + ctx_b
__global__ __launch_bounds__(128) void ctxw_k(const float* __restrict__ ctx0,
    const float* __restrict__ W, const float* __restrict__ bias, float* __restrict__ out)
{
  int b = blockIdx.x; int n = (blockIdx.y<<7) + threadIdx.x;
  const float* c = ctx0 + (b<<10);
  float acc = bias[n];
  for (int k=0;k<1024;++k) acc = fmaf(c[k], W[((size_t)k<<10)+n], acc);
  out[(b<<10)+n] = acc;
}

// ---------------------------------------------------------------------------
// router: warp/adj/direct/boost/gate_scores + top-3 selection
// ---------------------------------------------------------------------------
__global__ __launch_bounds__(256) void router_k(
    const float* __restrict__ ctx,
    const float* __restrict__ summaries, const float* __restrict__ base_adj,
    const float* __restrict__ warp_w, const float* __restrict__ warp_b,
    const float* __restrict__ gate_w, const float* __restrict__ gate_b,
    float* __restrict__ out_gs, float* __restrict__ out_adj, float* __restrict__ out_hops,
    int* __restrict__ idx_out)
{
  __shared__ float sw[4][64], sd[4][8], sg[4][8], sgs[4][8];
  int tid = threadIdx.x;
  int b = tid >> 6, o = tid & 63;
  {
    const float* c = ctx + (b<<10);
    float acc = warp_b[o];
    for (int k=0;k<1024;++k) acc = fmaf(c[k], warp_w[(k<<6)+o], acc);
    sw[b][o] = acc * 0.1f;
  }
  __syncthreads();
  if (tid < 32) {
    int bb = tid >> 3, r = tid & 7;
    const float* c = ctx + (bb<<10);
    const float* s = summaries + (r<<10);
    float a = 0.f;
    for (int k=0;k<1024;++k) a = fmaf(c[k], s[k], a);
    sd[bb][r] = a;
  } else if (tid < 64) {
    int t2 = tid - 32; int bb = t2 >> 3, r = t2 & 7;
    const float* c = ctx + (bb<<10);
    float a = gate_b[r];
    for (int k=0;k<1024;++k) a = fmaf(c[k], gate_w[(k<<3)+r], a);
    sg[bb][r] = a;
  }
  __syncthreads();
  if (tid < 32) {
    int bb = tid >> 3, i = tid & 7;
    float e[8], mx = -3.0e38f;
    #pragma unroll
    for (int j=0;j<8;++j) { e[j] = base_adj[(i<<3)+j] + sw[bb][(i<<3)+j]; mx = fmaxf(mx, e[j]); }
    float ssum = 0.f;
    #pragma unroll
    for (int j=0;j<8;++j) { e[j] = __expf(e[j]-mx); ssum += e[j]; }
    float inv = 1.0f/ssum, boost = 0.f;
    #pragma unroll
    for (int j=0;j<8;++j) {
      float a = e[j]*inv;
      out_adj[((bb<<3)+i)*8 + j] = a;
      boost = fmaf(a, sd[bb][j], boost);
    }
    float gs = sigmoid_f((sg[bb][i] + boost)*0.5f);
    sgs[bb][i] = gs;
    out_gs[(bb<<3)+i] = gs;
  }
  __syncthreads();
  if (tid == 0) {
    float mg[8];
    #pragma unroll
    for (int r=0;r<8;++r) mg[r] = (sgs[0][r]+sgs[1][r]+sgs[2][r]+sgs[3][r])*0.25f;
    bool used[8] = {false,false,false,false,false,false,false,false};
    for (int h=0; h<3; ++h) {              // jax top_k: descending, ties -> lower idx
      int best = 0; float bvv = -3.0e38f;
      for (int r=0;r<8;++r) if (!used[r] && mg[r] > bvv) { bvv = mg[r]; best = r; }
      used[best] = true; idx_out[h] = best;
    }
    out_hops[0] = 3.0f;                    // MAX_HOPS
  }
}

// ---------------------------------------------------------------------------
// per-room soft gate: sigmoid(gelu(ctx@g1+b1)@g2 + b2), one block per batch b
// ---------------------------------------------------------------------------
__global__ __launch_bounds__(256) void gate_k(
    const float* __restrict__ ctxr,
    const float* __restrict__ g1w, const float* __restrict__ g1b,
    const float* __restrict__ g2w, const float* __restrict__ g2b,
    const int* __restrict__ didx, int hop,
    float* __restrict__ gate_out, float* __restrict__ gm_out)
{
  __shared__ float sred[4];
  int b = blockIdx.x, j = threadIdx.x, room = didx[hop];
  const float* W = g1w + (size_t)room*1024*256;
  const float* c = ctxr + (b<<10);
  float acc = g1b[room*256 + j];
  for (int k=0;k<1024;++k) acc = fmaf(c[k], W[(k<<8)+j], acc);
  float contrib = gelu_f(acc) * g2w[room*256 + j];
  #pragma unroll
  for (int off=32; off; off>>=1) contrib += __shfl_xor(contrib, off, 64);
  if ((j & 63) == 0) sred[j>>6] = contrib;
  __syncthreads();
  if (j == 0) {
    float tot = sred[0]+sred[1]+sred[2]+sred[3] + g2b[room];
    float g = sigmoid_f(tot);
    gate_out[b] = g;
    atomicAdd(gm_out, g*0.25f);
  }
}

// ---------------------------------------------------------------------------
// layernorm (one block per token row); ln1 mode: apply gate, write xg fp32;
// always writes normalized row as f16
// ---------------------------------------------------------------------------
__global__ __launch_bounds__(256) void ln_k(
    const float* __restrict__ xin, const float* __restrict__ gate,
    const float* __restrict__ gbase, const float* __restrict__ bbase,
    const int* __restrict__ didx, int hop,
    float* __restrict__ xg_out, f16* __restrict__ nrm_out)
{
  __shared__ float sred[4];
  int row = blockIdx.x;
  int b = row >> 10;
  int room = didx[hop];
  int tid = threadIdx.x;
  float gv = gate ? gate[b] : 1.0f;
  fx4 v = *(const fx4*)(xin + ((size_t)row<<10) + (tid<<2));
  v *= gv;
  if (xg_out) *(fx4*)(xg_out + ((size_t)row<<10) + (tid<<2)) = v;

  float s = v[0]+v[1]+v[2]+v[3];
  #pragma unroll
  for (int off=32; off; off>>=1) s += __shfl_xor(s, off, 64);
  if ((tid&63)==0) sred[tid>>6] = s;
  __syncthreads();
  float mean = (sred[0]+sred[1]+sred[2]+sred[3]) * (1.0f/1024.0f);
  __syncthreads();

  fx4 dv = v - mean;
  float q = dv[0]*dv[0]+dv[1]*dv[1]+dv[2]*dv[2]+dv[3]*dv[3];
  #pragma unroll
  for (int off=32; off; off>>=1) q += __shfl_xor(q, off, 64);
  if ((tid&63)==0) sred[tid>>6] = q;
  __syncthreads();
  float var = (sred[0]+sred[1]+sred[2]+sred[3]) * (1.0f/1024.0f);
  float rstd = rsqrtf(var + 1e-5f);

  fx4 gg = *(const fx4*)(gbase + ((size_t)room<<10) + (tid<<2));
  fx4 bb = *(const fx4*)(bbase + ((size_t)room<<10) + (tid<<2));
  fx4 ov = dv*rstd*gg + bb;
  f16x4 h; h[0]=(f16)ov[0]; h[1]=(f16)ov[1]; h[2]=(f16)ov[2]; h[3]=(f16)ov[3];
  *(f16x4*)(nrm_out + ((size_t)row<<10) + (tid<<2)) = h;
}

// ---------------------------------------------------------------------------
// causal flash attention, fp32 VALU. 4 threads per q row (DH split 16 each),
// 512-thread block = 128 q rows. q pre-scaled by 1/sqrt(DH).
// Writes o as f16 in (B,T,D) layout.
// ---------------------------------------------------------------------------
__global__ __launch_bounds__(512) void attn_k(
    const float* __restrict__ q, const float* __restrict__ k, const float* __restrict__ v,
    f16* __restrict__ o)
{
  __shared__ __align__(16) float Kt[64*64];
  __shared__ __align__(16) float Vt[64*64];
  int bh = blockIdx.y;
  int q0 = (gridDim.x - 1 - blockIdx.x) << 7;   // heavy (high-q0) blocks first
  int tid = threadIdx.x;
  int ql = tid >> 2, qt = tid & 3;              // q row / DH quarter
  int qrow = q0 + ql;
  const float* qp = q + ((size_t)bh<<16) + ((size_t)qrow<<6) + (qt<<4);

  fx4 qr4[4], oa4[4];
  #pragma unroll
  for (int i=0;i<4;++i) { qr4[i] = *(const fx4*)(qp + (i<<2)); oa4[i] = (fx4){0.f,0.f,0.f,0.f}; }
  float mrun = -3.0e38f, lrun = 0.f;
  int ntile = (q0 >> 6) + 2;
  const float* kbp = k + ((size_t)bh<<16);
  const float* vbp = v + ((size_t)bh<<16);
  int lrow = tid >> 3, lseg = (tid & 7) << 3;   // tile-load coords

  for (int kt=0; kt<ntile; ++kt) {
    int k0 = kt<<6;
    __syncthreads();
    {
      const float* ks = kbp + ((size_t)(k0+lrow)<<6) + lseg;
      const float* vs = vbp + ((size_t)(k0+lrow)<<6) + lseg;
      float* kd = Kt + (lrow<<6) + lseg;
      float* vd = Vt + (lrow<<6) + lseg;
      *(fx4*)(kd)   = *(const fx4*)(ks);
      *(fx4*)(kd+4) = *(const fx4*)(ks+4);
      *(fx4*)(vd)   = *(const fx4*)(vs);
      *(fx4*)(vd+4) = *(const fx4*)(vs+4);
    }
    __syncthreads();

    #pragma unroll
    for (int sh=0; sh<2; ++sh) {
      int kbase = k0 + (sh<<5);
      if (kbase <= qrow) {
        float sv[32];
        float tmax = -3.0e38f;
        #pragma unroll
        for (int j=0;j<32;++j) {
          const float* kr = Kt + ((sh*32+j)<<6) + (qt<<4);
          fx4 a4 = (fx4){0.f,0.f,0.f,0.f};
          #pragma unroll
          for (int i=0;i<4;++i) a4 += qr4[i] * (*(const fx4*)(kr + (i<<2)));
          float s = (a4[0]+a4[1])+(a4[2]+a4[3]);
          s += __shfl_xor(s, 1);
          s += __shfl_xor(s, 2);                 // full 64-dot across the 4 lanes
          s = (kbase + j <= qrow) ? s : -3.0e38f;
          sv[j] = s; tmax = fmaxf(tmax, s);
        }
        float mnew = fmaxf(mrun, tmax);
        float alpha = __expf(mrun - mnew);
        lrun *= alpha;
        #pragma unroll
        for (int d=0; d<4; ++d) oa4[d] *= alpha;
        #pragma unroll
        for (int j=0;j<32;++j) {
          float p = __expf(sv[j]-mnew);
          lrun += p;
          const float* vr = Vt + ((sh*32+j)<<6) + (qt<<4);
          #pragma unroll
          for (int d=0; d<4; ++d) oa4[d] += p * (*(const fx4*)(vr + (d<<2)));
        }
        mrun = mnew;
      }
    }
  }
  float inv = 1.0f/lrun;
  int b = bh >> 4, hh = bh & 15;
  f16* op = o + (((size_t)(b<<10) + qrow)<<10) + (hh<<6) + (qt<<4);
  #pragma unroll
  for (int d=0; d<4; ++d) {
    fx4 t = oa4[d]*inv;
    f16x4 hv; hv[0]=(f16)t[0]; hv[1]=(f16)t[1]; hv[2]=(f16)t[2]; hv[3]=(f16)t[3];
    *(f16x4*)(op + (d<<2)) = hv;
  }
}

// ---------------------------------------------------------------------------
extern "C" void kernel_launch(void* const* d_in, const int* in_sizes, int n_in,
                              void* d_out, int out_size, void* d_ws, size_t ws_size,
                              hipStream_t stream)
{
  const float* x      = (const float*)d_in[0];
  const float* summ   = (const float*)d_in[1];
  const float* ctx_w  = (const float*)d_in[2];
  const float* ctx_b  = (const float*)d_in[3];
  const float* base_adj=(const float*)d_in[4];
  const float* warp_w = (const float*)d_in[5];
  const float* warp_b = (const float*)d_in[6];
  const float* gate_w = (const float*)d_in[7];
  const float* gate_b = (const float*)d_in[8];
  const float* g1w    = (const float*)d_in[9];
  const float* g1b    = (const float*)d_in[10];
  const float* g2w    = (const float*)d_in[11];
  const float* g2b    = (const float*)d_in[12];
  const float* ln1g   = (const float*)d_in[13];
  const float* ln1b   = (const float*)d_in[14];
  const float* wq     = (const float*)d_in[15];
  const float* bq     = (const float*)d_in[16];
  const float* wk     = (const float*)d_in[17];
  const float* bk     = (const float*)d_in[18];
  const float* wv     = (const float*)d_in[19];
  const float* bvp    = (const float*)d_in[20];
  const float* wo     = (const float*)d_in[21];
  const float* bo     = (const float*)d_in[22];
  const float* ln2g   = (const float*)d_in[23];
  const float* ln2b   = (const float*)d_in[24];
  const float* ff1w   = (const float*)d_in[25];
  const float* ff1b   = (const float*)d_in[26];
  const float* ff2w   = (const float*)d_in[27];
  const float* ff2b   = (const float*)d_in[28];
  (void)in_sizes; (void)n_in; (void)out_size; (void)ws_size;

  float* ws = (float*)d_ws;
  size_t off = 0;
  auto alloc = [&](size_t n){ float* p = ws + off; off += n; return p; };

  float* x_cur = alloc(NTOKc);
  float* xg    = alloc(NTOKc);
  float* xo    = alloc(NTOKc);
  float* qkv   = alloc(3*NTOKc);             // q,k,v contiguous (B,H,T,DH) each
  f16*  h1     = (f16*)qkv;                  // ff1 out overlays q+k (8M f16 < 8M floats)
  float* ctx0  = alloc(4096);
  float* ctxT  = alloc(4096);
  float* ctxR  = alloc(4096);
  float* part  = alloc(32768);
  float* gatev = alloc(8);
  float* gmv   = alloc(8);
  int*   idxv  = (int*)alloc(8);
  f16* nrm  = (f16*)alloc(NTOKc/2);          // f16 normed (ln1 & ln2 reuse)
  f16* ofb  = (f16*)alloc(NTOKc/2);          // f16 attention output
  f16* wqkvT= (f16*)alloc(1572864);          // 3072 x 1024 f16
  f16* woT  = (f16*)alloc(524288);
  f16* ff1T = (f16*)alloc(2097152);          // 4096 x 1024 f16
  f16* ff2T = (f16*)alloc(2097152);          // 1024 x 4096 f16

  hipMemcpyAsync(x_cur, x, NTOKc*sizeof(float), hipMemcpyDeviceToDevice, stream);

  // ---- router ----
  rowmean_s1<<<dim3(4,4,8),256,0,stream>>>(x, part);
  rowmean_s2<<<dim3(4,4),256,0,stream>>>(part, ctx0, nullptr);
  ctxw_k<<<dim3(4,8),128,0,stream>>>(ctx0, ctx_w, ctx_b, ctxT);
  float* out_gs   = (float*)d_out + NTOKc;
  float* out_adj  = out_gs + 32;
  float* out_hops = out_adj + 256;
  router_k<<<1,256,0,stream>>>(ctxT, summ, base_adj, warp_w, warp_b, gate_w, gate_b,
                               out_gs, out_adj, out_hops, idxv);

  // ---- 3 hops ----
  for (int hop=0; hop<3; ++hop) {
    rowmean_s1<<<dim3(4,4,8),256,0,stream>>>(x_cur, part);
    rowmean_s2<<<dim3(4,4),256,0,stream>>>(part, ctxR, gmv);   // also zeroes gm

    wconv4<<<dim3(16,16,4),256,0,stream>>>(wq, wk, wv, wo,
        wqkvT, wqkvT + (size_t)1024*1024, wqkvT + (size_t)2048*1024, woT, idxv, hop);
    wconv<<<dim3(64,16),256,0,stream>>>(ff1w, ff1T, idxv, hop, 1024, 4096);
    wconv<<<dim3(16,64),256,0,stream>>>(ff2w, ff2T, idxv, hop, 4096, 1024);

    gate_k<<<4,256,0,stream>>>(ctxR, g1w, g1b, g2w, g2b, idxv, hop, gatev, gmv);
    ln_k<<<4096,256,0,stream>>>(x_cur, gatev, ln1g, ln1b, idxv, hop, xg, nrm);

    // fused QKV: N=3072, 768 blocks (3/CU)
    gemm_f16<128><<<dim3(24,32),256,0,stream>>>(nrm, wqkvT, bq, bk, bvp, idxv, hop,
        BTc, 3072, 1024, KQKV, nullptr, nullptr, qkv, nullptr);

    attn_k<<<dim3(8,64),512,0,stream>>>(qkv, qkv + NTOKc, qkv + 2*NTOKc, ofb);

    // wo: N=1024 -> BM=64 variant (512 blocks, 2/CU)
    gemm_f16<64><<<dim3(8,64),256,0,stream>>>(ofb, woT, bo, nullptr, nullptr, idxv, hop,
        BTc, 1024, 1024, KWO, xg, nullptr, xo, nullptr);
    ln_k<<<4096,256,0,stream>>>(xo, nullptr, ln2g, ln2b, idxv, hop, nullptr, nrm);
    gemm_f16<128><<<dim3(32,32),256,0,stream>>>(nrm, ff1T, ff1b, nullptr, nullptr, idxv, hop,
        BTc, 4096, 1024, KFF1, nullptr, nullptr, nullptr, h1);
    gemm_f16<64><<<dim3(8,64),256,0,stream>>>(h1, ff2T, ff2b, nullptr, nullptr, idxv, hop,
        BTc, 1024, 4096, KFF2, xo, gmv, x_cur, nullptr);
  }

  hipMemcpyAsync(d_out, x_cur, NTOKc*sizeof(float), hipMemcpyDeviceToDevice, stream);
}